// Round 2
// baseline (145.137 us; speedup 1.0000x reference)
//
#include <hip/hip_runtime.h>
#include <hip/hip_bf16.h>

// ProbabilisticMap: out[b][x][y][t] = scale(b,t) * exp(-0.5 * d^T inv(cov(b,t)) d),
// d = (x,y) - mean(b,t); mean/cov are Bernstein-weighted sums over <=8 control pts.
//
// Round 4: two-kernel split (round 3) got 171.5 -> 141.7 us, but map still ran
// ~2.6 TB/s vs the 6.6 TB/s the harness's own fillBuffer proves for pure write
// streams. Difference: fill stores dwordx4 (1024 B/wave-instr), map stored
// dword (256 B/wave-instr, 4x the store instrs + address work), and each block
// wrote only 16 KiB behind an L2-latency prologue. This round:
//   - map: each thread owns 4 consecutive t -> float4 stores (1024 B/wave)
//   - map: 4 x-rows per block (grid 2048, 64 KiB/block, prologue amortized)
// Arithmetic per element is bit-identical to the verified round-3 kernel.
//
// Layouts (C-order):
//   cp_means: (K=8, B=128, 2)     fp32 (or bf16 -- detected)
//   num_cps : (B=128,)            int32 (or int64 -- detected)
//   cp_cov  : (K=8, B=128, 2, 2)  fp32 (or bf16 -- detected)
//   out     : (B=128, W=64, H=64, T=64) fp32  -> 128 MiB
//   ws      : (B=128, T=64, 8) fp32 = 256 KiB  {mx,my,g00,gxy,g11,sc,0,0}

#define MAP_W 64
#define MAP_H 64
#define T_SIZE 64
#define NUM_CP 8
#define BATCH 128
#define STATS_F 8   // floats per (b,t) stat record (padded to 32 B)

// Per-(b,t) Bernstein-weighted mean/cov -> folded inverse + scale.
// Numerics identical (same ops, same order) to the verified round-2 kernel.
__device__ __forceinline__ void bezier_stats(
    const void* __restrict__ cp_means_p,
    const void* __restrict__ num_cps_p,
    const void* __restrict__ cp_cov_p,
    const int b, const int t_i,
    float& mx_o, float& my_o, float& g00_o, float& gxy_o, float& g11_o, float& sc_o)
{
    // ---- runtime dtype detection (wave-uniform, deterministic) ----
    const int* ni32 = (const int*)num_cps_p;
    const bool is_i64 = (ni32[1] == 0);              // values 3..8, never 0
    const int  ncp = is_i64 ? (int)((const long long*)num_cps_p)[b] : ni32[b];
    const int  n   = ncp - 1;                        // 2..7

    const __hip_bfloat16* mbv = (const __hip_bfloat16*)cp_means_p;
    const __hip_bfloat16* cbv = (const __hip_bfloat16*)cp_cov_p;
    const float*          mf  = (const float*)cp_means_p;
    const float*          cf  = (const float*)cp_cov_p;
    // means are in [0,63]; fp32 data viewed as bf16 has random low-halves
    bool is_f32 = false;
    #pragma unroll
    for (int i = 0; i < 32; ++i) {
        const float v = __bfloat162float(mbv[i]);
        if (!(v >= 0.0f && v <= 64.0f)) is_f32 = true;   // NaN lands here too
    }

    // t = linspace(0,1,64)[t_i]
    const float t   = (float)t_i * (1.0f / 63.0f);
    const float omt = 1.0f - t;

    float mx = 0.f, my = 0.f, ca = 0.f, cb = 0.f, cc = 0.f, cd = 0.f;
    float ck = 1.0f, tk = 1.0f;
    #pragma unroll
    for (int k = 0; k < NUM_CP; ++k) {
        const int e = n - k;
        float onk = (e == 0) ? 1.0f : 0.0f;
        float o = 1.0f;
        #pragma unroll
        for (int j = 1; j < NUM_CP; ++j) { o *= omt; if (e == j) onk = o; }
        const float w  = (k <= n) ? ck * tk * onk : 0.0f;
        const float w2 = w * w;
        const int base = k * BATCH + b;
        const float m0 = is_f32 ? mf[base*2+0] : __bfloat162float(mbv[base*2+0]);
        const float m1 = is_f32 ? mf[base*2+1] : __bfloat162float(mbv[base*2+1]);
        const float q0 = is_f32 ? cf[base*4+0] : __bfloat162float(cbv[base*4+0]);
        const float q1 = is_f32 ? cf[base*4+1] : __bfloat162float(cbv[base*4+1]);
        const float q2 = is_f32 ? cf[base*4+2] : __bfloat162float(cbv[base*4+2]);
        const float q3 = is_f32 ? cf[base*4+3] : __bfloat162float(cbv[base*4+3]);
        mx = fmaf(w,  m0, mx);
        my = fmaf(w,  m1, my);
        ca = fmaf(w2, q0, ca);
        cb = fmaf(w2, q1, cb);
        cc = fmaf(w2, q2, cc);
        cd = fmaf(w2, q3, cd);
        ck = ck * (float)(n - k) / (float)(k + 1);
        tk *= t;
    }

    // 2x2 inverse folded with -0.5*log2(e) -> inner loop uses native exp2
    const float det     = fmaf(ca, cd, -(cb * cc));  // > 0
    const float inv_det = 1.0f / det;
    const float HL2E    = 0.72134752044448170368f;   // 0.5 * log2(e)
    mx_o  = mx;
    my_o  = my;
    g00_o = -HL2E * cd * inv_det;
    gxy_o =  HL2E * (cb + cc) * inv_det;
    g11_o = -HL2E * ca * inv_det;
    sc_o  = 0.15915494309189535f / sqrtf(det);       // 1/(2*pi*sqrt(det))
}

// ---- kernel 1: stats. 8192 threads = 32 blocks x 256. gid = b*64 + t. ----
__global__ __launch_bounds__(256) void stats_kernel(
    const void* __restrict__ cp_means_p,
    const void* __restrict__ num_cps_p,
    const void* __restrict__ cp_cov_p,
    float* __restrict__ ws)
{
    const int gid = blockIdx.x * 256 + threadIdx.x;  // (b<<6) | t
    const int b   = gid >> 6;
    const int t_i = gid & 63;

    float mx, my, g00, gxy, g11, sc;
    bezier_stats(cp_means_p, num_cps_p, cp_cov_p, b, t_i, mx, my, g00, gxy, g11, sc);

    float4* w4 = (float4*)(ws + (size_t)gid * STATS_F);
    w4[0] = make_float4(mx, my, g00, gxy);
    w4[1] = make_float4(g11, sc, 0.0f, 0.0f);
}

// ---- kernel 2: map. One block per (b, x-quad); float4 write stream. ----
// grid = B*16 = 2048 blocks, 256 threads. Thread (tg = tid&15, y0 = tid>>4)
// owns t = tg*4..tg*4+3, writes float4 at y = y0, y0+16, y0+32, y0+48 for
// each of the block's 4 x rows. Wave store = 64 lanes x 16 B = 1024 B
// contiguous (y rows are 256 B apart and covered by the 4 y0-groups).
__global__ __launch_bounds__(256) void map_kernel(
    const float* __restrict__ ws,
    float* __restrict__ out)
{
    const int tid = threadIdx.x;
    const int blk = blockIdx.x;          // b*16 + xg
    const int b   = blk >> 4;
    const int x0  = (blk & 15) << 2;     // first of this block's 4 x rows
    const int tg  = tid & 15;            // t-group: t = tg*4 + j
    const int y0  = tid >> 4;            // 0..15

    // per-thread stats for 4 consecutive t (L1/L2-resident: 256 KiB total)
    float mx[4], my[4], g00[4], gxy[4], g11[4], sc[4];
    #pragma unroll
    for (int j = 0; j < 4; ++j) {
        const float4* s4 = (const float4*)(ws + ((size_t)((b << 6) | (tg * 4 + j))) * STATS_F);
        const float4 s0 = s4[0];
        const float4 s1 = s4[1];
        mx[j]  = s0.x;  my[j]  = s0.y;
        g00[j] = s0.z;  gxy[j] = s0.w;
        g11[j] = s1.x;  sc[j]  = s1.y;
    }

    #pragma unroll
    for (int xi = 0; xi < 4; ++xi) {
        const int   x  = x0 + xi;
        const float fx = (float)x;
        // fold row-uniform x (same expression order as the verified kernel)
        float c0[4], c1[4];
        #pragma unroll
        for (int j = 0; j < 4; ++j) {
            const float dx = fx - mx[j];
            c0[j] = g00[j] * dx * dx;
            c1[j] = gxy[j] * dx;
        }

        float4* __restrict__ orow =
            (float4*)(out + ((size_t)((b << 6) | x) << 12)) + tg;

        #pragma unroll
        for (int yi = 0; yi < 4; ++yi) {
            const int   y  = y0 + (yi << 4);
            const float fy = (float)y;
            float4 v;
            {
                const float dy = fy - my[0];
                v.x = sc[0] * exp2f(fmaf(dy, fmaf(g11[0], dy, c1[0]), c0[0]));
            }
            {
                const float dy = fy - my[1];
                v.y = sc[1] * exp2f(fmaf(dy, fmaf(g11[1], dy, c1[1]), c0[1]));
            }
            {
                const float dy = fy - my[2];
                v.z = sc[2] * exp2f(fmaf(dy, fmaf(g11[2], dy, c1[2]), c0[2]));
            }
            {
                const float dy = fy - my[3];
                v.w = sc[3] * exp2f(fmaf(dy, fmaf(g11[3], dy, c1[3]), c0[3]));
            }
            orow[y << 4] = v;   // 16 B per lane; wave = 1024 B contiguous
        }
    }
}

// ---- fallback: verified single kernel (used if ws too small) ----
__global__ __launch_bounds__(256) void pmap_kernel(
    const void* __restrict__ cp_means_p,
    const void* __restrict__ num_cps_p,
    const void* __restrict__ cp_cov_p,
    float* __restrict__ out)
{
    __shared__ float s_my[T_SIZE], s_g11[T_SIZE], s_c0[T_SIZE], s_c1[T_SIZE], s_sc[T_SIZE];

    const int tid = threadIdx.x;
    const int blk = blockIdx.x;        // blk = b*64 + x
    const int b   = blk >> 6;
    const int x   = blk & 63;

    if (tid < T_SIZE) {
        float mx, my, g00, gxy, g11, sc;
        bezier_stats(cp_means_p, num_cps_p, cp_cov_p, b, tid, mx, my, g00, gxy, g11, sc);
        const float dx = (float)x - mx;
        s_my[tid]  = my;
        s_g11[tid] = g11;
        s_c0[tid]  = g00 * dx * dx;
        s_c1[tid]  = gxy * dx;
        s_sc[tid]  = sc;
    }
    __syncthreads();

    const int t_idx = tid & 63;
    const int y0    = tid >> 6;
    const float my  = s_my[t_idx];
    const float g11 = s_g11[t_idx];
    const float c0  = s_c0[t_idx];
    const float c1  = s_c1[t_idx];
    const float sc  = s_sc[t_idx];

    float* __restrict__ orow = out + ((size_t)blk << 12) + t_idx;

    #pragma unroll
    for (int y = y0; y < MAP_H; y += 4) {
        const float dy  = (float)y - my;
        const float arg = fmaf(dy, fmaf(g11, dy, c1), c0);
        orow[y << 6] = sc * exp2f(arg);
    }
}

extern "C" void kernel_launch(void* const* d_in, const int* in_sizes, int n_in,
                              void* d_out, int out_size, void* d_ws, size_t ws_size,
                              hipStream_t stream) {
    const size_t ws_needed = (size_t)BATCH * T_SIZE * STATS_F * sizeof(float); // 256 KiB
    if (d_ws != nullptr && ws_size >= ws_needed) {
        stats_kernel<<<dim3((BATCH * T_SIZE) / 256), dim3(256), 0, stream>>>(
            d_in[0], d_in[1], d_in[2], (float*)d_ws);
        map_kernel<<<dim3(BATCH * (MAP_W / 4)), dim3(256), 0, stream>>>(
            (const float*)d_ws, (float*)d_out);
    } else {
        pmap_kernel<<<dim3(BATCH * MAP_W), dim3(256), 0, stream>>>(
            d_in[0], d_in[1], d_in[2], (float*)d_out);
    }
}